// Round 6
// baseline (258.906 us; speedup 1.0000x reference)
//
#include <hip/hip_runtime.h>

// GetWeightMatrix: weight = 1 + 1.5 * sum_{5x5 shifts}(y_pad != argmax_c(x))
// x: [8, 21, 512, 512] f32, y: [8, 512, 512] i32, out: [8, 1, 512, 512] f32
//
// Round 6: two-pass split retained (R5: kernel slice 56 -> 46 us). Pass-1
// argmax estimated ~38 us = 4.6 TB/s vs 6.8 TB/s fills -> issue/latency gap.
// Change: pass-1 goes 4 -> 8 px/thread (two f32x4 per channel, 8 loads = 8 KB
// in flight per wave, half the address/issue overhead per pixel). ~60 VGPR,
// (256,4) cap -> zero spill (round-1 lesson: never buy occupancy with spills).
// Pass 2 unchanged for clean attribution. Fallback fused kernel if ws < 2 MB.

typedef float f32x4 __attribute__((ext_vector_type(4)));
typedef int   i32x4 __attribute__((ext_vector_type(4)));

constexpr int B = 8;
constexpr int C = 21;
constexpr int W = 512;
constexpr int H = 512;
constexpr int PIX = W * H;
constexpr int NGROUP = B * PIX / 4;   // 524288 4-pixel groups (pass 2 / fallback)
constexpr int NG8    = B * PIX / 8;   // 262144 8-pixel groups (pass 1)

// ---------------- Pass 1: argmax over channels, 8 px/thread ----------------
__global__ __launch_bounds__(256, 4) void argmax_kernel(
    const float* __restrict__ x, uint2* __restrict__ amap)
{
    const int tid = blockIdx.x * blockDim.x + threadIdx.x;
    const int gpi = PIX / 8;          // 32768 8-pixel groups per image
    const int b   = tid / gpi;
    const int g   = tid - b * gpi;

    const float* xp = x + (size_t)b * C * PIX + (size_t)g * 8;
    f32x4 bestA = __builtin_nontemporal_load((const f32x4*)xp);
    f32x4 bestB = __builtin_nontemporal_load((const f32x4*)(xp + 4));
    int aA0 = 0, aA1 = 0, aA2 = 0, aA3 = 0;
    int aB0 = 0, aB1 = 0, aB2 = 0, aB3 = 0;

#define STEP_A(v, c)                                            \
    do {                                                        \
        if ((v)[0] > bestA[0]) { bestA[0] = (v)[0]; aA0 = (c); }\
        if ((v)[1] > bestA[1]) { bestA[1] = (v)[1]; aA1 = (c); }\
        if ((v)[2] > bestA[2]) { bestA[2] = (v)[2]; aA2 = (c); }\
        if ((v)[3] > bestA[3]) { bestA[3] = (v)[3]; aA3 = (c); }\
    } while (0)
#define STEP_B(v, c)                                            \
    do {                                                        \
        if ((v)[0] > bestB[0]) { bestB[0] = (v)[0]; aB0 = (c); }\
        if ((v)[1] > bestB[1]) { bestB[1] = (v)[1]; aB1 = (c); }\
        if ((v)[2] > bestB[2]) { bestB[2] = (v)[2]; aB2 = (c); }\
        if ((v)[3] > bestB[3]) { bestB[3] = (v)[3]; aB3 = (c); }\
    } while (0)

#pragma unroll
    for (int grp = 0; grp < 5; ++grp) {
        const int c0 = 4 * grp + 1;   // channels 1..20 in 5 groups of 4
        const float* p0 = xp + (size_t)(c0 + 0) * PIX;
        const float* p1 = xp + (size_t)(c0 + 1) * PIX;
        const float* p2 = xp + (size_t)(c0 + 2) * PIX;
        const float* p3 = xp + (size_t)(c0 + 3) * PIX;
        f32x4 v0a = __builtin_nontemporal_load((const f32x4*)p0);
        f32x4 v0b = __builtin_nontemporal_load((const f32x4*)(p0 + 4));
        f32x4 v1a = __builtin_nontemporal_load((const f32x4*)p1);
        f32x4 v1b = __builtin_nontemporal_load((const f32x4*)(p1 + 4));
        f32x4 v2a = __builtin_nontemporal_load((const f32x4*)p2);
        f32x4 v2b = __builtin_nontemporal_load((const f32x4*)(p2 + 4));
        f32x4 v3a = __builtin_nontemporal_load((const f32x4*)p3);
        f32x4 v3b = __builtin_nontemporal_load((const f32x4*)(p3 + 4));
        STEP_A(v0a, c0 + 0); STEP_B(v0b, c0 + 0);
        STEP_A(v1a, c0 + 1); STEP_B(v1b, c0 + 1);
        STEP_A(v2a, c0 + 2); STEP_B(v2b, c0 + 2);
        STEP_A(v3a, c0 + 3); STEP_B(v3b, c0 + 3);
    }
#undef STEP_A
#undef STEP_B

    // pack 8 argmax bytes (labels 0..20); uint2 index tid == u32 indices
    // {2*tid, 2*tid+1} of the NGROUP-sized map pass 2 reads.
    uint2 packed;
    packed.x = (unsigned int)aA0 | ((unsigned int)aA1 << 8) |
               ((unsigned int)aA2 << 16) | ((unsigned int)aA3 << 24);
    packed.y = (unsigned int)aB0 | ((unsigned int)aB1 << 8) |
               ((unsigned int)aB2 << 16) | ((unsigned int)aB3 << 24);
    amap[tid] = packed;
}

// ---------------- Pass 2: 5x5 neighborhood mismatch count ----------------
__global__ __launch_bounds__(256, 4) void weight_kernel(
    const unsigned int* __restrict__ amap, const int* __restrict__ y,
    float* __restrict__ out)
{
    const int tid = blockIdx.x * blockDim.x + threadIdx.x;
    const int gpr = H / 4;
    const int gpi = W * gpr;
    const int b   = tid / gpi;
    const int rem = tid - b * gpi;
    const int w   = rem / gpr;
    const int h   = (rem - w * gpr) << 2;

    // pass-1 linear pixel order == w*H + h, so u32 index tid matches.
    const unsigned int packed = amap[tid];
    const int am0 = (int)(packed & 0xFFu);
    const int am1 = (int)((packed >> 8) & 0xFFu);
    const int am2 = (int)((packed >> 16) & 0xFFu);
    const int am3 = (int)((packed >> 24) & 0xFFu);

    const int* yb = y + b * PIX;
    const i32x4 zero4 = {0, 0, 0, 0};
    int cnt0 = 0, cnt1 = 0, cnt2 = 0, cnt3 = 0;
#pragma unroll
    for (int di = 0; di < 5; ++di) {
        const int ww = w + di - 2;
        const bool wok = (unsigned)ww < (unsigned)W;   // wave-uniform
        const int* yrow = yb + ww * H;
        // 3 aligned int4 loads cover h-4..h+7; needed window h-2..h+5 = elems 2..9.
        // OOB chunks -> 0 (= Unfold zero-pad label).
        i32x4 ca = (wok && h >= 4)     ? *(const i32x4*)(yrow + h - 4) : zero4;
        i32x4 cb = wok                 ? *(const i32x4*)(yrow + h)     : zero4;
        i32x4 cc = (wok && h <= H - 8) ? *(const i32x4*)(yrow + h + 4) : zero4;
        const int yr[12] = {ca[0], ca[1], ca[2], ca[3],
                            cb[0], cb[1], cb[2], cb[3],
                            cc[0], cc[1], cc[2], cc[3]};
#pragma unroll
        for (int dj = 0; dj < 5; ++dj) {
            cnt0 += (yr[2 + 0 + dj] != am0) ? 1 : 0;
            cnt1 += (yr[2 + 1 + dj] != am1) ? 1 : 0;
            cnt2 += (yr[2 + 2 + dj] != am2) ? 1 : 0;
            cnt3 += (yr[2 + 3 + dj] != am3) ? 1 : 0;
        }
    }

    f32x4 res;
    res[0] = 1.0f + 1.5f * (float)cnt0;
    res[1] = 1.0f + 1.5f * (float)cnt1;
    res[2] = 1.0f + 1.5f * (float)cnt2;
    res[3] = 1.0f + 1.5f * (float)cnt3;
    __builtin_nontemporal_store(res, (f32x4*)(out + (size_t)b * PIX + (size_t)w * H + h));
}

// ---------------- Fallback: fused (round-4 kernel, known-correct) ----------------
__global__ __launch_bounds__(256, 4) void getweight_fused(
    const float* __restrict__ x, const int* __restrict__ y,
    float* __restrict__ out)
{
    const int tid = blockIdx.x * blockDim.x + threadIdx.x;
    const int gpr = H / 4;
    const int gpi = W * gpr;
    const int b   = tid / gpi;
    const int rem = tid - b * gpi;
    const int w   = rem / gpr;
    const int h   = (rem - w * gpr) << 2;

    const float* xp = x + (size_t)b * C * PIX + (size_t)w * H + h;
    f32x4 best = __builtin_nontemporal_load((const f32x4*)xp);
    int am0 = 0, am1 = 0, am2 = 0, am3 = 0;
#define ARGMAX_STEP(v, c)                                      \
    do {                                                       \
        if ((v)[0] > best[0]) { best[0] = (v)[0]; am0 = (c); } \
        if ((v)[1] > best[1]) { best[1] = (v)[1]; am1 = (c); } \
        if ((v)[2] > best[2]) { best[2] = (v)[2]; am2 = (c); } \
        if ((v)[3] > best[3]) { best[3] = (v)[3]; am3 = (c); } \
    } while (0)
#pragma unroll
    for (int g = 0; g < 5; ++g) {
        const int c0 = 4 * g + 1;
        f32x4 v0 = __builtin_nontemporal_load((const f32x4*)(xp + (size_t)(c0 + 0) * PIX));
        f32x4 v1 = __builtin_nontemporal_load((const f32x4*)(xp + (size_t)(c0 + 1) * PIX));
        f32x4 v2 = __builtin_nontemporal_load((const f32x4*)(xp + (size_t)(c0 + 2) * PIX));
        f32x4 v3 = __builtin_nontemporal_load((const f32x4*)(xp + (size_t)(c0 + 3) * PIX));
        ARGMAX_STEP(v0, c0 + 0);
        ARGMAX_STEP(v1, c0 + 1);
        ARGMAX_STEP(v2, c0 + 2);
        ARGMAX_STEP(v3, c0 + 3);
    }
#undef ARGMAX_STEP

    const int* yb = y + b * PIX;
    const i32x4 zero4 = {0, 0, 0, 0};
    int cnt0 = 0, cnt1 = 0, cnt2 = 0, cnt3 = 0;
#pragma unroll
    for (int di = 0; di < 5; ++di) {
        const int ww = w + di - 2;
        const bool wok = (unsigned)ww < (unsigned)W;
        const int* yrow = yb + ww * H;
        i32x4 ca = (wok && h >= 4)     ? *(const i32x4*)(yrow + h - 4) : zero4;
        i32x4 cb = wok                 ? *(const i32x4*)(yrow + h)     : zero4;
        i32x4 cc = (wok && h <= H - 8) ? *(const i32x4*)(yrow + h + 4) : zero4;
        const int yr[12] = {ca[0], ca[1], ca[2], ca[3],
                            cb[0], cb[1], cb[2], cb[3],
                            cc[0], cc[1], cc[2], cc[3]};
#pragma unroll
        for (int dj = 0; dj < 5; ++dj) {
            cnt0 += (yr[2 + 0 + dj] != am0) ? 1 : 0;
            cnt1 += (yr[2 + 1 + dj] != am1) ? 1 : 0;
            cnt2 += (yr[2 + 2 + dj] != am2) ? 1 : 0;
            cnt3 += (yr[2 + 3 + dj] != am3) ? 1 : 0;
        }
    }

    f32x4 res;
    res[0] = 1.0f + 1.5f * (float)cnt0;
    res[1] = 1.0f + 1.5f * (float)cnt1;
    res[2] = 1.0f + 1.5f * (float)cnt2;
    res[3] = 1.0f + 1.5f * (float)cnt3;
    __builtin_nontemporal_store(res, (f32x4*)(out + (size_t)b * PIX + (size_t)w * H + h));
}

extern "C" void kernel_launch(void* const* d_in, const int* in_sizes, int n_in,
                              void* d_out, int out_size, void* d_ws, size_t ws_size,
                              hipStream_t stream) {
    const float* x = (const float*)d_in[0];   // [8,21,512,512] f32
    const int*   y = (const int*)d_in[1];     // [8,512,512] i32
    float* out = (float*)d_out;               // [8,1,512,512] f32

    const int block = 256;

    if (d_ws != nullptr && ws_size >= (size_t)NGROUP * sizeof(unsigned int)) {
        uint2* amap = (uint2*)d_ws;           // 2 MB packed argmax map
        argmax_kernel<<<NG8 / block, block, 0, stream>>>(x, amap);
        weight_kernel<<<NGROUP / block, block, 0, stream>>>(
            (const unsigned int*)amap, y, out);
    } else {
        getweight_fused<<<NGROUP / block, block, 0, stream>>>(x, y, out);
    }
}

// Round 7
// 239.079 us; speedup vs baseline: 1.0829x; 1.0829x over previous
//
#include <hip/hip_runtime.h>

// GetWeightMatrix: weight = 1 + 1.5 * sum_{5x5 shifts}(y_pad != argmax_c(x))
// x: [8, 21, 512, 512] f32, y: [8, 512, 512] i32, out: [8, 1, 512, 512] f32
//
// Round 7: fix R6's coalescing bug. R6 gave lane i pixels g*8..g*8+7 ->
// per-instruction lane stride 32 B with 16 B used: each dwordx4 touched 32
// half-filled cache lines (2x TA transactions/instr) -> pass-1 38 -> 67 us.
// Now each thread owns TWO wave-contiguous 4-px groups: gA in this wave's
// first 1 KB block, gB = gA+64 in the next -> every load instruction covers a
// fully-coalesced contiguous 1 KB, second load folds to offset:1024. Keeps
// the doubled per-thread MLP and reads 2 KB sequential per channel per wave
// (better DRAM row locality). Clean A/B vs R6: only the layout changed.
// Pass 2 unchanged. Fallback fused kernel if ws < 2 MB.

typedef float f32x4 __attribute__((ext_vector_type(4)));
typedef int   i32x4 __attribute__((ext_vector_type(4)));

constexpr int B = 8;
constexpr int C = 21;
constexpr int W = 512;
constexpr int H = 512;
constexpr int PIX = W * H;
constexpr int NGROUP = B * PIX / 4;   // 524288 4-pixel groups (pass 2 / fallback)
constexpr int NPAIR  = B * PIX / 8;   // 262144 group-pairs (pass 1)

// ---------------- Pass 1: argmax over channels, 2x4 px/thread ----------------
__global__ __launch_bounds__(256, 4) void argmax_kernel(
    const float* __restrict__ x, unsigned int* __restrict__ amap)
{
    const int tid = blockIdx.x * blockDim.x + threadIdx.x;
    const int ppi = PIX / 8;          // 32768 pairs per image
    const int b   = tid / ppi;
    const int p   = tid - b * ppi;
    // lane-contiguous mapping: wave w covers groups [w*128, w*128+127] as two
    // contiguous 64-group (1 KB) blocks.
    const int gA  = ((p >> 6) << 7) + (p & 63);   // first 4-px group
    // gB = gA + 64  (handled as +256 floats = offset:1024 on the same pointer)

    const float* xp = x + (size_t)b * C * PIX + (size_t)gA * 4;
    f32x4 bestA = __builtin_nontemporal_load((const f32x4*)xp);
    f32x4 bestB = __builtin_nontemporal_load((const f32x4*)(xp + 256));
    int aA0 = 0, aA1 = 0, aA2 = 0, aA3 = 0;
    int aB0 = 0, aB1 = 0, aB2 = 0, aB3 = 0;

#define STEP_A(v, c)                                            \
    do {                                                        \
        if ((v)[0] > bestA[0]) { bestA[0] = (v)[0]; aA0 = (c); }\
        if ((v)[1] > bestA[1]) { bestA[1] = (v)[1]; aA1 = (c); }\
        if ((v)[2] > bestA[2]) { bestA[2] = (v)[2]; aA2 = (c); }\
        if ((v)[3] > bestA[3]) { bestA[3] = (v)[3]; aA3 = (c); }\
    } while (0)
#define STEP_B(v, c)                                            \
    do {                                                        \
        if ((v)[0] > bestB[0]) { bestB[0] = (v)[0]; aB0 = (c); }\
        if ((v)[1] > bestB[1]) { bestB[1] = (v)[1]; aB1 = (c); }\
        if ((v)[2] > bestB[2]) { bestB[2] = (v)[2]; aB2 = (c); }\
        if ((v)[3] > bestB[3]) { bestB[3] = (v)[3]; aB3 = (c); }\
    } while (0)

#pragma unroll
    for (int grp = 0; grp < 5; ++grp) {
        const int c0 = 4 * grp + 1;   // channels 1..20 in 5 groups of 4
        const float* p0 = xp + (size_t)(c0 + 0) * PIX;
        const float* p1 = xp + (size_t)(c0 + 1) * PIX;
        const float* p2 = xp + (size_t)(c0 + 2) * PIX;
        const float* p3 = xp + (size_t)(c0 + 3) * PIX;
        f32x4 v0a = __builtin_nontemporal_load((const f32x4*)p0);
        f32x4 v0b = __builtin_nontemporal_load((const f32x4*)(p0 + 256));
        f32x4 v1a = __builtin_nontemporal_load((const f32x4*)p1);
        f32x4 v1b = __builtin_nontemporal_load((const f32x4*)(p1 + 256));
        f32x4 v2a = __builtin_nontemporal_load((const f32x4*)p2);
        f32x4 v2b = __builtin_nontemporal_load((const f32x4*)(p2 + 256));
        f32x4 v3a = __builtin_nontemporal_load((const f32x4*)p3);
        f32x4 v3b = __builtin_nontemporal_load((const f32x4*)(p3 + 256));
        STEP_A(v0a, c0 + 0); STEP_B(v0b, c0 + 0);
        STEP_A(v1a, c0 + 1); STEP_B(v1b, c0 + 1);
        STEP_A(v2a, c0 + 2); STEP_B(v2b, c0 + 2);
        STEP_A(v3a, c0 + 3); STEP_B(v3b, c0 + 3);
    }
#undef STEP_A
#undef STEP_B

    // pack 4 argmax bytes per group; map layout = [b][group] u32, matching
    // pass 2's linear tid. Two stores, each wave-contiguous (256 B).
    const int mbase = b * (PIX / 4);
    amap[mbase + gA] = (unsigned int)aA0 | ((unsigned int)aA1 << 8) |
                       ((unsigned int)aA2 << 16) | ((unsigned int)aA3 << 24);
    amap[mbase + gA + 64] = (unsigned int)aB0 | ((unsigned int)aB1 << 8) |
                            ((unsigned int)aB2 << 16) | ((unsigned int)aB3 << 24);
}

// ---------------- Pass 2: 5x5 neighborhood mismatch count ----------------
__global__ __launch_bounds__(256, 4) void weight_kernel(
    const unsigned int* __restrict__ amap, const int* __restrict__ y,
    float* __restrict__ out)
{
    const int tid = blockIdx.x * blockDim.x + threadIdx.x;
    const int gpr = H / 4;
    const int gpi = W * gpr;
    const int b   = tid / gpi;
    const int rem = tid - b * gpi;
    const int w   = rem / gpr;
    const int h   = (rem - w * gpr) << 2;

    // pass-1 linear pixel order == w*H + h, so u32 index tid matches.
    const unsigned int packed = amap[tid];
    const int am0 = (int)(packed & 0xFFu);
    const int am1 = (int)((packed >> 8) & 0xFFu);
    const int am2 = (int)((packed >> 16) & 0xFFu);
    const int am3 = (int)((packed >> 24) & 0xFFu);

    const int* yb = y + b * PIX;
    const i32x4 zero4 = {0, 0, 0, 0};
    int cnt0 = 0, cnt1 = 0, cnt2 = 0, cnt3 = 0;
#pragma unroll
    for (int di = 0; di < 5; ++di) {
        const int ww = w + di - 2;
        const bool wok = (unsigned)ww < (unsigned)W;   // wave-uniform
        const int* yrow = yb + ww * H;
        // 3 aligned int4 loads cover h-4..h+7; needed window h-2..h+5 = elems 2..9.
        // OOB chunks -> 0 (= Unfold zero-pad label).
        i32x4 ca = (wok && h >= 4)     ? *(const i32x4*)(yrow + h - 4) : zero4;
        i32x4 cb = wok                 ? *(const i32x4*)(yrow + h)     : zero4;
        i32x4 cc = (wok && h <= H - 8) ? *(const i32x4*)(yrow + h + 4) : zero4;
        const int yr[12] = {ca[0], ca[1], ca[2], ca[3],
                            cb[0], cb[1], cb[2], cb[3],
                            cc[0], cc[1], cc[2], cc[3]};
#pragma unroll
        for (int dj = 0; dj < 5; ++dj) {
            cnt0 += (yr[2 + 0 + dj] != am0) ? 1 : 0;
            cnt1 += (yr[2 + 1 + dj] != am1) ? 1 : 0;
            cnt2 += (yr[2 + 2 + dj] != am2) ? 1 : 0;
            cnt3 += (yr[2 + 3 + dj] != am3) ? 1 : 0;
        }
    }

    f32x4 res;
    res[0] = 1.0f + 1.5f * (float)cnt0;
    res[1] = 1.0f + 1.5f * (float)cnt1;
    res[2] = 1.0f + 1.5f * (float)cnt2;
    res[3] = 1.0f + 1.5f * (float)cnt3;
    __builtin_nontemporal_store(res, (f32x4*)(out + (size_t)b * PIX + (size_t)w * H + h));
}

// ---------------- Fallback: fused (round-4 kernel, known-correct) ----------------
__global__ __launch_bounds__(256, 4) void getweight_fused(
    const float* __restrict__ x, const int* __restrict__ y,
    float* __restrict__ out)
{
    const int tid = blockIdx.x * blockDim.x + threadIdx.x;
    const int gpr = H / 4;
    const int gpi = W * gpr;
    const int b   = tid / gpi;
    const int rem = tid - b * gpi;
    const int w   = rem / gpr;
    const int h   = (rem - w * gpr) << 2;

    const float* xp = x + (size_t)b * C * PIX + (size_t)w * H + h;
    f32x4 best = __builtin_nontemporal_load((const f32x4*)xp);
    int am0 = 0, am1 = 0, am2 = 0, am3 = 0;
#define ARGMAX_STEP(v, c)                                      \
    do {                                                       \
        if ((v)[0] > best[0]) { best[0] = (v)[0]; am0 = (c); } \
        if ((v)[1] > best[1]) { best[1] = (v)[1]; am1 = (c); } \
        if ((v)[2] > best[2]) { best[2] = (v)[2]; am2 = (c); } \
        if ((v)[3] > best[3]) { best[3] = (v)[3]; am3 = (c); } \
    } while (0)
#pragma unroll
    for (int g = 0; g < 5; ++g) {
        const int c0 = 4 * g + 1;
        f32x4 v0 = __builtin_nontemporal_load((const f32x4*)(xp + (size_t)(c0 + 0) * PIX));
        f32x4 v1 = __builtin_nontemporal_load((const f32x4*)(xp + (size_t)(c0 + 1) * PIX));
        f32x4 v2 = __builtin_nontemporal_load((const f32x4*)(xp + (size_t)(c0 + 2) * PIX));
        f32x4 v3 = __builtin_nontemporal_load((const f32x4*)(xp + (size_t)(c0 + 3) * PIX));
        ARGMAX_STEP(v0, c0 + 0);
        ARGMAX_STEP(v1, c0 + 1);
        ARGMAX_STEP(v2, c0 + 2);
        ARGMAX_STEP(v3, c0 + 3);
    }
#undef ARGMAX_STEP

    const int* yb = y + b * PIX;
    const i32x4 zero4 = {0, 0, 0, 0};
    int cnt0 = 0, cnt1 = 0, cnt2 = 0, cnt3 = 0;
#pragma unroll
    for (int di = 0; di < 5; ++di) {
        const int ww = w + di - 2;
        const bool wok = (unsigned)ww < (unsigned)W;
        const int* yrow = yb + ww * H;
        i32x4 ca = (wok && h >= 4)     ? *(const i32x4*)(yrow + h - 4) : zero4;
        i32x4 cb = wok                 ? *(const i32x4*)(yrow + h)     : zero4;
        i32x4 cc = (wok && h <= H - 8) ? *(const i32x4*)(yrow + h + 4) : zero4;
        const int yr[12] = {ca[0], ca[1], ca[2], ca[3],
                            cb[0], cb[1], cb[2], cb[3],
                            cc[0], cc[1], cc[2], cc[3]};
#pragma unroll
        for (int dj = 0; dj < 5; ++dj) {
            cnt0 += (yr[2 + 0 + dj] != am0) ? 1 : 0;
            cnt1 += (yr[2 + 1 + dj] != am1) ? 1 : 0;
            cnt2 += (yr[2 + 2 + dj] != am2) ? 1 : 0;
            cnt3 += (yr[2 + 3 + dj] != am3) ? 1 : 0;
        }
    }

    f32x4 res;
    res[0] = 1.0f + 1.5f * (float)cnt0;
    res[1] = 1.0f + 1.5f * (float)cnt1;
    res[2] = 1.0f + 1.5f * (float)cnt2;
    res[3] = 1.0f + 1.5f * (float)cnt3;
    __builtin_nontemporal_store(res, (f32x4*)(out + (size_t)b * PIX + (size_t)w * H + h));
}

extern "C" void kernel_launch(void* const* d_in, const int* in_sizes, int n_in,
                              void* d_out, int out_size, void* d_ws, size_t ws_size,
                              hipStream_t stream) {
    const float* x = (const float*)d_in[0];   // [8,21,512,512] f32
    const int*   y = (const int*)d_in[1];     // [8,512,512] i32
    float* out = (float*)d_out;               // [8,1,512,512] f32

    const int block = 256;

    if (d_ws != nullptr && ws_size >= (size_t)NGROUP * sizeof(unsigned int)) {
        unsigned int* amap = (unsigned int*)d_ws;   // 2 MB packed argmax map
        argmax_kernel<<<NPAIR / block, block, 0, stream>>>(x, amap);
        weight_kernel<<<NGROUP / block, block, 0, stream>>>(amap, y, out);
    } else {
        getweight_fused<<<NGROUP / block, block, 0, stream>>>(x, y, out);
    }
}

// Round 8
// 238.680 us; speedup vs baseline: 1.0847x; 1.0017x over previous
//
#include <hip/hip_runtime.h>

// GetWeightMatrix: weight = 1 + 1.5 * sum_{5x5 shifts}(y_pad != argmax_c(x))
// x: [8, 21, 512, 512] f32, y: [8, 512, 512] i32, out: [8, 1, 512, 512] f32
//
// Round 8: pass-1 kept EXACTLY as R7 (three configs R5/R7 with 2x TLP and 2x
// MLP variation all sit at 4.6 TB/s read -> pass-1 is at the read-path
// ceiling for this 21-stream pattern, not latency-bound). This round targets
// pass-2: 8 px/thread, clamped-address row loads (wok is wave-uniform now:
// one wave = one image row), edge zero-pad via 4 cndmasks instead of per-lane
// load predication, uint2 amap load, 2x float4 stores. 23 vmem per 8 px
// (2.9/px) vs 17 per 4 px (4.25/px). Predict pass-2 ~8 -> ~5 us.
// Pre-commit: if dur_us within +-2 us of R7 (239), declare roofline.

typedef float f32x4 __attribute__((ext_vector_type(4)));
typedef int   i32x4 __attribute__((ext_vector_type(4)));

constexpr int B = 8;
constexpr int C = 21;
constexpr int W = 512;
constexpr int H = 512;
constexpr int PIX = W * H;
constexpr int NGROUP = B * PIX / 4;   // 524288 4-px groups (fallback / map size)
constexpr int NPAIR  = B * PIX / 8;   // 262144 pass-1 threads (2x4 px each)
constexpr int NOCT   = B * PIX / 8;   // 262144 pass-2 threads (8 px each)

// ---------------- Pass 1: argmax over channels, 2x4 px/thread (R7) ----------------
__global__ __launch_bounds__(256, 4) void argmax_kernel(
    const float* __restrict__ x, unsigned int* __restrict__ amap)
{
    const int tid = blockIdx.x * blockDim.x + threadIdx.x;
    const int ppi = PIX / 8;          // 32768 pairs per image
    const int b   = tid / ppi;
    const int p   = tid - b * ppi;
    // lane-contiguous mapping: wave w covers groups [w*128, w*128+127] as two
    // contiguous 64-group (1 KB) blocks.
    const int gA  = ((p >> 6) << 7) + (p & 63);   // first 4-px group

    const float* xp = x + (size_t)b * C * PIX + (size_t)gA * 4;
    f32x4 bestA = __builtin_nontemporal_load((const f32x4*)xp);
    f32x4 bestB = __builtin_nontemporal_load((const f32x4*)(xp + 256));
    int aA0 = 0, aA1 = 0, aA2 = 0, aA3 = 0;
    int aB0 = 0, aB1 = 0, aB2 = 0, aB3 = 0;

#define STEP_A(v, c)                                            \
    do {                                                        \
        if ((v)[0] > bestA[0]) { bestA[0] = (v)[0]; aA0 = (c); }\
        if ((v)[1] > bestA[1]) { bestA[1] = (v)[1]; aA1 = (c); }\
        if ((v)[2] > bestA[2]) { bestA[2] = (v)[2]; aA2 = (c); }\
        if ((v)[3] > bestA[3]) { bestA[3] = (v)[3]; aA3 = (c); }\
    } while (0)
#define STEP_B(v, c)                                            \
    do {                                                        \
        if ((v)[0] > bestB[0]) { bestB[0] = (v)[0]; aB0 = (c); }\
        if ((v)[1] > bestB[1]) { bestB[1] = (v)[1]; aB1 = (c); }\
        if ((v)[2] > bestB[2]) { bestB[2] = (v)[2]; aB2 = (c); }\
        if ((v)[3] > bestB[3]) { bestB[3] = (v)[3]; aB3 = (c); }\
    } while (0)

#pragma unroll
    for (int grp = 0; grp < 5; ++grp) {
        const int c0 = 4 * grp + 1;   // channels 1..20 in 5 groups of 4
        const float* p0 = xp + (size_t)(c0 + 0) * PIX;
        const float* p1 = xp + (size_t)(c0 + 1) * PIX;
        const float* p2 = xp + (size_t)(c0 + 2) * PIX;
        const float* p3 = xp + (size_t)(c0 + 3) * PIX;
        f32x4 v0a = __builtin_nontemporal_load((const f32x4*)p0);
        f32x4 v0b = __builtin_nontemporal_load((const f32x4*)(p0 + 256));
        f32x4 v1a = __builtin_nontemporal_load((const f32x4*)p1);
        f32x4 v1b = __builtin_nontemporal_load((const f32x4*)(p1 + 256));
        f32x4 v2a = __builtin_nontemporal_load((const f32x4*)p2);
        f32x4 v2b = __builtin_nontemporal_load((const f32x4*)(p2 + 256));
        f32x4 v3a = __builtin_nontemporal_load((const f32x4*)p3);
        f32x4 v3b = __builtin_nontemporal_load((const f32x4*)(p3 + 256));
        STEP_A(v0a, c0 + 0); STEP_B(v0b, c0 + 0);
        STEP_A(v1a, c0 + 1); STEP_B(v1b, c0 + 1);
        STEP_A(v2a, c0 + 2); STEP_B(v2b, c0 + 2);
        STEP_A(v3a, c0 + 3); STEP_B(v3b, c0 + 3);
    }
#undef STEP_A
#undef STEP_B

    const int mbase = b * (PIX / 4);
    amap[mbase + gA] = (unsigned int)aA0 | ((unsigned int)aA1 << 8) |
                       ((unsigned int)aA2 << 16) | ((unsigned int)aA3 << 24);
    amap[mbase + gA + 64] = (unsigned int)aB0 | ((unsigned int)aB1 << 8) |
                            ((unsigned int)aB2 << 16) | ((unsigned int)aB3 << 24);
}

// ---------------- Pass 2: 5x5 mismatch count, 8 px/thread ----------------
__global__ __launch_bounds__(256, 4) void weight_kernel(
    const uint2* __restrict__ amap2, const int* __restrict__ y,
    float* __restrict__ out)
{
    const int tid = blockIdx.x * blockDim.x + threadIdx.x;
    const int tpr = H / 8;            // 64 threads per row -> one wave = one row
    const int tpi = W * tpr;          // 32768 per image
    const int b   = tid / tpi;
    const int rem = tid - b * tpi;
    const int w   = rem / tpr;
    const int h   = (rem - w * tpr) << 3;   // base col of this thread's 8 px

    // amap uint2 index: b*(PIX/8) + (w*H+h)/8 == tid (linear layouts match)
    const uint2 am8 = amap2[tid];
    int am[8];
#pragma unroll
    for (int j = 0; j < 4; ++j) {
        am[j]     = (int)((am8.x >> (8 * j)) & 0xFFu);
        am[j + 4] = (int)((am8.y >> (8 * j)) & 0xFFu);
    }

    // Clamped col bases (always in-bounds, 16B aligned since h%8==0):
    //   ca covers cols ha..ha+3   (normally h-4..h-1; clamped to 0..3   at h==0)
    //   cd covers cols hd..hd+3   (normally h+8..h+11; clamped to 508.. at h==504)
    const int ha = (h >= 4) ? h - 4 : 0;
    const int hd = (h <= H - 12) ? h + 8 : H - 4;
    const bool lo = (h == 0);         // yr[2],yr[3] (cols -2,-1) are pad
    const bool hi = (h == H - 8);     // yr[12],yr[13] (cols 512,513) are pad

    const int* yb = y + b * PIX;
    const i32x4 zero4 = {0, 0, 0, 0};
    int cnt[8] = {0, 0, 0, 0, 0, 0, 0, 0};
#pragma unroll
    for (int di = 0; di < 5; ++di) {
        const int ww = w + di - 2;
        const bool wok = (unsigned)ww < (unsigned)W;   // WAVE-uniform (1 wave = 1 row)
        const int* yrow = yb + ww * H;
        i32x4 ca = wok ? *(const i32x4*)(yrow + ha)    : zero4;
        i32x4 cb = wok ? *(const i32x4*)(yrow + h)     : zero4;
        i32x4 cc = wok ? *(const i32x4*)(yrow + h + 4) : zero4;
        i32x4 cd = wok ? *(const i32x4*)(yrow + hd)    : zero4;
        // Window cols h-4..h+11; used range is yr[2..13] (cols h-2..h+9).
        // Edge fixups: zero the 4 cells that are zero-pad at image borders
        // (yr[0],yr[1],yr[14],yr[15] may hold clamped garbage but are unused).
        const int yr[16] = {ca[0], ca[1],
                            lo ? 0 : ca[2], lo ? 0 : ca[3],
                            cb[0], cb[1], cb[2], cb[3],
                            cc[0], cc[1], cc[2], cc[3],
                            hi ? 0 : cd[0], hi ? 0 : cd[1],
                            cd[2], cd[3]};
#pragma unroll
        for (int j = 0; j < 8; ++j) {
#pragma unroll
            for (int dj = 0; dj < 5; ++dj) {
                cnt[j] += (yr[j + 2 + dj] != am[j]) ? 1 : 0;
            }
        }
    }

    f32x4 r0, r1;
#pragma unroll
    for (int j = 0; j < 4; ++j) {
        r0[j] = 1.0f + 1.5f * (float)cnt[j];
        r1[j] = 1.0f + 1.5f * (float)cnt[j + 4];
    }
    float* op = out + (size_t)b * PIX + (size_t)w * H + h;
    __builtin_nontemporal_store(r0, (f32x4*)op);
    __builtin_nontemporal_store(r1, (f32x4*)(op + 4));
}

// ---------------- Fallback: fused (round-4 kernel, known-correct) ----------------
__global__ __launch_bounds__(256, 4) void getweight_fused(
    const float* __restrict__ x, const int* __restrict__ y,
    float* __restrict__ out)
{
    const int tid = blockIdx.x * blockDim.x + threadIdx.x;
    const int gpr = H / 4;
    const int gpi = W * gpr;
    const int b   = tid / gpi;
    const int rem = tid - b * gpi;
    const int w   = rem / gpr;
    const int h   = (rem - w * gpr) << 2;

    const float* xp = x + (size_t)b * C * PIX + (size_t)w * H + h;
    f32x4 best = __builtin_nontemporal_load((const f32x4*)xp);
    int am0 = 0, am1 = 0, am2 = 0, am3 = 0;
#define ARGMAX_STEP(v, c)                                      \
    do {                                                       \
        if ((v)[0] > best[0]) { best[0] = (v)[0]; am0 = (c); } \
        if ((v)[1] > best[1]) { best[1] = (v)[1]; am1 = (c); } \
        if ((v)[2] > best[2]) { best[2] = (v)[2]; am2 = (c); } \
        if ((v)[3] > best[3]) { best[3] = (v)[3]; am3 = (c); } \
    } while (0)
#pragma unroll
    for (int g = 0; g < 5; ++g) {
        const int c0 = 4 * g + 1;
        f32x4 v0 = __builtin_nontemporal_load((const f32x4*)(xp + (size_t)(c0 + 0) * PIX));
        f32x4 v1 = __builtin_nontemporal_load((const f32x4*)(xp + (size_t)(c0 + 1) * PIX));
        f32x4 v2 = __builtin_nontemporal_load((const f32x4*)(xp + (size_t)(c0 + 2) * PIX));
        f32x4 v3 = __builtin_nontemporal_load((const f32x4*)(xp + (size_t)(c0 + 3) * PIX));
        ARGMAX_STEP(v0, c0 + 0);
        ARGMAX_STEP(v1, c0 + 1);
        ARGMAX_STEP(v2, c0 + 2);
        ARGMAX_STEP(v3, c0 + 3);
    }
#undef ARGMAX_STEP

    const int* yb = y + b * PIX;
    const i32x4 zero4 = {0, 0, 0, 0};
    int cnt0 = 0, cnt1 = 0, cnt2 = 0, cnt3 = 0;
#pragma unroll
    for (int di = 0; di < 5; ++di) {
        const int ww = w + di - 2;
        const bool wok = (unsigned)ww < (unsigned)W;
        const int* yrow = yb + ww * H;
        i32x4 ca = (wok && h >= 4)     ? *(const i32x4*)(yrow + h - 4) : zero4;
        i32x4 cb = wok                 ? *(const i32x4*)(yrow + h)     : zero4;
        i32x4 cc = (wok && h <= H - 8) ? *(const i32x4*)(yrow + h + 4) : zero4;
        const int yr[12] = {ca[0], ca[1], ca[2], ca[3],
                            cb[0], cb[1], cb[2], cb[3],
                            cc[0], cc[1], cc[2], cc[3]};
#pragma unroll
        for (int dj = 0; dj < 5; ++dj) {
            cnt0 += (yr[2 + 0 + dj] != am0) ? 1 : 0;
            cnt1 += (yr[2 + 1 + dj] != am1) ? 1 : 0;
            cnt2 += (yr[2 + 2 + dj] != am2) ? 1 : 0;
            cnt3 += (yr[2 + 3 + dj] != am3) ? 1 : 0;
        }
    }

    f32x4 res;
    res[0] = 1.0f + 1.5f * (float)cnt0;
    res[1] = 1.0f + 1.5f * (float)cnt1;
    res[2] = 1.0f + 1.5f * (float)cnt2;
    res[3] = 1.0f + 1.5f * (float)cnt3;
    __builtin_nontemporal_store(res, (f32x4*)(out + (size_t)b * PIX + (size_t)w * H + h));
}

extern "C" void kernel_launch(void* const* d_in, const int* in_sizes, int n_in,
                              void* d_out, int out_size, void* d_ws, size_t ws_size,
                              hipStream_t stream) {
    const float* x = (const float*)d_in[0];   // [8,21,512,512] f32
    const int*   y = (const int*)d_in[1];     // [8,512,512] i32
    float* out = (float*)d_out;               // [8,1,512,512] f32

    const int block = 256;

    if (d_ws != nullptr && ws_size >= (size_t)NGROUP * sizeof(unsigned int)) {
        unsigned int* amap = (unsigned int*)d_ws;   // 2 MB packed argmax map
        argmax_kernel<<<NPAIR / block, block, 0, stream>>>(x, amap);
        weight_kernel<<<NOCT / block, block, 0, stream>>>(
            (const uint2*)amap, y, out);
    } else {
        getweight_fused<<<NGROUP / block, block, 0, stream>>>(x, y, out);
    }
}